// Round 14
// baseline (97.106 us; speedup 1.0000x reference)
//
#include <hip/hip_runtime.h>
#include <hip/hip_bf16.h>
#include <stdint.h>
#include <math.h>

#define NROWS  8192
#define DIM    768                        // elements per row
#define DIMB   384                        // bytes per row in fp4 (4 bits/elem)
#define BKB    64                         // K-tile bytes (128 elements)
#define NKT    6                          // 768 / 128
#define BM     256
#define BN     128
#define EPSV   1e-6f
#define NTI    32                         // 8192/BM
#define NTJ    64                         // 8192/BN
#define NJN    (NTI * NTJ)                // 2048 X-vs-Y tiles
#define NJJ    1056                       // JJ tiles: sum_{ti}(64-2ti)
#define NBLK   (NJN + NJJ)                // 3104 = 8 * 388 (XCD-divisible)

typedef __attribute__((ext_vector_type(4))) int   int4v;
typedef __attribute__((ext_vector_type(8))) int   int8v;
typedef __attribute__((ext_vector_type(4))) float f32x4;
typedef unsigned char uchar;

// async global->LDS, 16B per lane; LDS dest is wave-uniform base (+lane*16 by HW)
__device__ __forceinline__ void gload16(const void* g, void* l) {
    __builtin_amdgcn_global_load_lds(
        (const __attribute__((address_space(1))) void*)g,
        (__attribute__((address_space(3))) void*)l,
        16, 0, 0);
}

// fp32 -> fp4 e2m1 nibble, round-to-nearest. Levels {0,.5,1,1.5,2,3,4,6}.
__device__ __forceinline__ uint32_t f2fp4(float x) {
    float a = fabsf(x);
    uint32_t c;
    if (a < 1.25f)      c = a < 0.25f ? 0u : (a < 0.75f ? 1u : 2u);
    else if (a < 2.5f)  c = a < 1.75f ? 3u : 4u;
    else                c = a < 3.5f ? 5u : (a < 5.0f ? 6u : 7u);
    return c | (x < 0.f ? 8u : 0u);
}

// ------- prep: fp4-e2m1 convert into Z=[X;Y], folded row stats (exact fp32) -------
// 2 rows per block: threads [0,128) = row 2*bid, [128,256) = row 2*bid+1.
__global__ __launch_bounds__(256)
void prep(const float* __restrict__ X, const float* __restrict__ Y,
          float* __restrict__ SXa, float* __restrict__ TB,
          uchar* __restrict__ Zf4) {
    const int row = 2 * blockIdx.x + (threadIdx.x >> 7);   // 0..16383
    const int tt  = threadIdx.x & 127;
    const bool isX = row < NROWS;
    const float* p = (isX ? X : Y) + (size_t)(isX ? row : row - NROWS) * DIM;
    uint32_t* q = (uint32_t*)(Zf4 + (size_t)row * DIMB);
    float s = 0.f, qs = 0.f;
    if (tt < 96) {                         // 96 * 8 = 768 elems
        float4 v0 = *(const float4*)(p + 8 * tt);
        float4 v1 = *(const float4*)(p + 8 * tt + 4);
        uint32_t u = f2fp4(v0.x)        | (f2fp4(v0.y) << 4)  |
                     (f2fp4(v0.z) << 8) | (f2fp4(v0.w) << 12) |
                     (f2fp4(v1.x) << 16)| (f2fp4(v1.y) << 20) |
                     (f2fp4(v1.z) << 24)| (f2fp4(v1.w) << 28);
        q[tt] = u;
        s  = v0.x+v0.y+v0.z+v0.w + v1.x+v1.y+v1.z+v1.w;
        qs = v0.x*v0.x+v0.y*v0.y+v0.z*v0.z+v0.w*v0.w
           + v1.x*v1.x+v1.y*v1.y+v1.z*v1.z+v1.w*v1.w;
    }
    #pragma unroll
    for (int o = 32; o; o >>= 1) { s += __shfl_down(s, o); qs += __shfl_down(qs, o); }
    __shared__ float sh[8];
    const int wave = threadIdx.x >> 6, lane = threadIdx.x & 63;
    if (lane == 0) { sh[wave] = s; sh[4 + wave] = qs; }
    __syncthreads();
    if (tt == 0) {                          // thread 0 (row even) and 128 (row odd)
        const int w0 = (threadIdx.x >> 7) * 2;
        float ss = sh[w0] + sh[w0 + 1];
        float qq = sh[4 + w0] + sh[4 + w0 + 1];
        if (isX) SXa[row] = qq + 2.f*EPSV*ss;
        TB[row] = qq - 2.f*EPSV*ss + (float)DIM*EPSV*EPSV;
    }
}

// ------- fused MX-fp4 GEMM, 256x128 tile, 8 waves (4Mx2N), 3-deep pipeline -------
// (r13 structure frozen: 73 us, zero spill, 2 blocks/CU. r14 deltas: undef-high
// fragments — fp4 cbsz=4 reads only low 4 operand regs, proven by r12/r13
// absmax 0.0 with zeroed highs — and unmasked JJ min-tracking: only the 64
// diagonal tiles false-trigger the exact path, which is fully masked/correct.)
// Register budget: acc 64 AGPR + 60 VGPR = 124 <= 128 cap at 2 blocks/CU.
// Do NOT add live state across barriers.
__global__ __launch_bounds__(512, 4)
void gemm_loss(const uchar* __restrict__ Z, const int* __restrict__ labels,
               const float* __restrict__ SXa, const float* __restrict__ TB,
               float4* __restrict__ partials) {
    // bijective XCD swizzle: 3104 = 8 * 388
    const int bid = (blockIdx.x & 7) * (NBLK / 8) + (blockIdx.x >> 3);
    const int t = threadIdx.x;

    int ti, tj, jrow0;                      // jrow0 = B-side row base in Z
    bool jj;
    if (bid < NJN) {
        jj = false; ti = bid >> 6; tj = bid & 63; jrow0 = NROWS + tj * BN;
    } else {
        jj = true;
        int u = bid - NJN;                  // 0..1055; row ti has 64-2ti entries
        int t0 = (int)((65.0 - sqrt(65.0*65.0 - 4.0*(double)u)) * 0.5);
        if (t0 < 0) t0 = 0; if (t0 > 31) t0 = 31;
        while (t0 < 31 && (t0 + 1) * (65 - (t0 + 1)) <= u) ++t0;
        while (t0 > 0  && t0 * (65 - t0) > u) --t0;
        ti = t0; tj = 2*ti + (u - ti * (65 - ti)); jrow0 = tj * BN;
    }
    const int i0 = ti * BM;
    const int tjc = tj * BN;                // B-side column base (labels/lt)

    __shared__ __align__(16) uchar Asm[3][BM * BKB];   // 16 KB per buf
    __shared__ __align__(16) uchar Bsm[3][BN * BKB];   // 8 KB per buf
    __shared__ float red[8][4];

    const int wave = t >> 6, lane = t & 63;
    const int wrow = wave >> 1;             // 0..3 (M quarter: 64 rows)
    const int wcol = wave & 1;              // 0..1 (N half: 64 cols)

    // staging: chunk = 16 rows x 64B = 1KB; lane l -> row +(l>>2), slot l&3;
    // inverse-swizzled global col bytes:
    const int cS = ((lane & 3) * 16) ^ (((lane >> 2) & 3) << 4);
    const uchar* pAs = Z + (size_t)(i0 + 16*wave + (lane >> 2))    * DIMB + cS;
    const uchar* pBs = Z + (size_t)(jrow0 + 16*wave + (lane >> 2)) * DIMB + cS;

    const int lrow = lane & 15;
    const int kc   = (lane >> 4) * 16;      // 16-byte K-slot per lane quarter

    f32x4 acc[4][4] = {};

#define STAGE(b, kb)                                                           \
    do {                                                                       \
        gload16(pAs + (kb), &Asm[b][wave * 1024]);                             \
        gload16(pAs + (size_t)128 * DIMB + (kb), &Asm[b][(wave + 8) * 1024]);  \
        gload16(pBs + (kb), &Bsm[b][wave * 1024]);                             \
    } while (0)

// fp4 operand: low 4 regs real, high 4 undef (HW ignores regs 4-7 at cbsz=4)
#define FRAG(v4) __builtin_shufflevector((v4), (v4), 0, 1, 2, 3, -1, -1, -1, -1)

#define COMPUTE(b)                                                             \
    do {                                                                       \
        int8v bfr[4];                                                          \
        _Pragma("unroll")                                                      \
        for (int ni = 0; ni < 4; ++ni) {                                       \
            int rr = wcol*64 + ni*16 + lrow;                                   \
            int4v lo = *(const int4v*)&Bsm[b][rr*64 + (kc ^ ((rr & 3) << 4))]; \
            bfr[ni] = FRAG(lo);                                                \
        }                                                                      \
        __builtin_amdgcn_s_setprio(1);                                         \
        _Pragma("unroll")                                                      \
        for (int mi = 0; mi < 4; ++mi) {                                       \
            int rr = wrow*64 + mi*16 + lrow;                                   \
            int4v lo = *(const int4v*)&Asm[b][rr*64 + (kc ^ ((rr & 3) << 4))]; \
            int8v afr = FRAG(lo);                                              \
            _Pragma("unroll")                                                  \
            for (int ni = 0; ni < 4; ++ni)                                     \
                acc[mi][ni] = __builtin_amdgcn_mfma_scale_f32_16x16x128_f8f6f4( \
                    afr, bfr[ni], acc[mi][ni], 4, 4,                           \
                    0, 0x7F7F7F7Fu, 0, 0x7F7F7F7Fu);                           \
        }                                                                      \
        __builtin_amdgcn_s_setprio(0);                                         \
    } while (0)

#define FENCE() asm volatile("" ::: "memory")
#define BAR()   do { FENCE(); __builtin_amdgcn_s_barrier(); FENCE(); } while (0)
#define VMW3()  asm volatile("s_waitcnt vmcnt(3)" ::: "memory")
#define VMW0()  asm volatile("s_waitcnt vmcnt(0)" ::: "memory")

    // prologue: stage tiles 0,1; retire tile 0 (VMW3 leaves tile 1's 3 in flight)
    STAGE(0, 0);
    STAGE(1, BKB);
    VMW3();
    BAR();

    #pragma unroll
    for (int kt = 0; kt < NKT; ++kt) {
        if (kt < NKT - 2) STAGE((kt + 2) % 3, (kt + 2) * BKB);
        COMPUTE(kt % 3);
        if (kt < NKT - 2)      { VMW3(); BAR(); }   // retire tile kt+1
        else if (kt == NKT - 2){ VMW0(); BAR(); }   // tail: tile kt+1 fully in
    }

    // -------- epilogue (C/D: col=lane&15, row=(lane>>4)*4+reg) --------
    const int il = wrow*64 + ((lane >> 4) << 2);  // + mi*16 + r
    const int jl = wcol*64 + (lane & 15);         // + ni*16

    float tbv[4];
    #pragma unroll
    for (int ni = 0; ni < 4; ++ni)
        tbv[ni] = TB[jrow0 + jl + ni*16];

    float pos = 0.f, neg = 0.f, cross = 0.f, cnt = 0.f;
    float mn = 1e30f;   // unmasked min of d2: diagonal tiles (64/3104) falsely
                        // trigger the exact path, which is fully masked-correct.

    if (jj) {
        int labj[4];
        #pragma unroll
        for (int ni = 0; ni < 4; ++ni)
            labj[ni] = labels[tjc + jl + ni*16];
        const bool fullup = (tj >= 2*ti + 2);    // tile strictly above diagonal
        #pragma unroll
        for (int mi = 0; mi < 4; ++mi) {
            float4 sx4 = *(const float4*)&SXa[i0 + il + mi*16];
            int4   la4 = *(const int4*)&labels[i0 + il + mi*16];
            float sxr[4] = {sx4.x, sx4.y, sx4.z, sx4.w};
            int   lar[4] = {la4.x, la4.y, la4.z, la4.w};
            #pragma unroll
            for (int ni = 0; ni < 4; ++ni)
                #pragma unroll
                for (int r = 0; r < 4; ++r) {
                    float d2 = __builtin_fmaf(-2.f, acc[mi][ni][r],
                                              sxr[r] + tbv[ni]);
                    bool lt   = fullup | ((i0 + il + mi*16 + r) < (tjc + jl + ni*16));
                    bool same = (lar[r] == labj[ni]);
                    if (lt & same) { pos += fmaxf(d2, 0.f); cnt += 1.f; }
                    mn = fminf(mn, d2);
                }
        }
    } else {
        #pragma unroll
        for (int mi = 0; mi < 4; ++mi) {
            float4 sx4 = *(const float4*)&SXa[i0 + il + mi*16];
            float sxr[4] = {sx4.x, sx4.y, sx4.z, sx4.w};
            #pragma unroll
            for (int ni = 0; ni < 4; ++ni)
                #pragma unroll
                for (int r = 0; r < 4; ++r) {
                    float d2 = __builtin_fmaf(-2.f, acc[mi][ni][r],
                                              sxr[r] + tbv[ni]);
                    mn = fminf(mn, d2);
                }
        }
    }

    // rare exact path: margin-active pair OR diagonal tile (self-contained masks)
    if (__any(mn < 1.f)) {
        int labj[4] = {0,0,0,0};
        if (jj)
            #pragma unroll
            for (int ni = 0; ni < 4; ++ni)
                labj[ni] = labels[tjc + jl + ni*16];
        const bool fullup = jj && (tj >= 2*ti + 2);
        #pragma unroll
        for (int mi = 0; mi < 4; ++mi) {
            float4 sx4 = *(const float4*)&SXa[i0 + il + mi*16];
            float sxr[4] = {sx4.x, sx4.y, sx4.z, sx4.w};
            int lar[4] = {0,0,0,0};
            if (jj) {
                int4 la4 = *(const int4*)&labels[i0 + il + mi*16];
                lar[0]=la4.x; lar[1]=la4.y; lar[2]=la4.z; lar[3]=la4.w;
            }
            #pragma unroll
            for (int ni = 0; ni < 4; ++ni)
                #pragma unroll
                for (int r = 0; r < 4; ++r) {
                    float d2 = __builtin_fmaf(-2.f, acc[mi][ni][r],
                                              sxr[r] + tbv[ni]);
                    d2 = fmaxf(d2, 0.f);
                    float dist = sqrtf(fmaxf(d2, 1e-12f));
                    float m = fmaxf(1.f - dist, 0.f);
                    float s2 = m * m;
                    if (jj) {
                        bool lt   = fullup | ((i0 + il + mi*16 + r) < (tjc + jl + ni*16));
                        bool same = (lar[r] == labj[ni]);
                        if (lt & !same) neg += s2;
                    } else {
                        cross += s2;
                    }
                }
        }
    }

    #pragma unroll
    for (int o = 32; o; o >>= 1) {
        pos   += __shfl_down(pos, o);
        neg   += __shfl_down(neg, o);
        cross += __shfl_down(cross, o);
        cnt   += __shfl_down(cnt, o);
    }
    if (lane == 0) { red[wave][0] = pos; red[wave][1] = neg;
                     red[wave][2] = cross; red[wave][3] = cnt; }
    __syncthreads();
    if (t == 0) {
        float4 v = {0.f, 0.f, 0.f, 0.f};
        #pragma unroll
        for (int w = 0; w < 8; ++w) {
            v.x += red[w][0]; v.y += red[w][1];
            v.z += red[w][2]; v.w += red[w][3];
        }
        partials[bid] = v;
    }
#undef STAGE
#undef COMPUTE
#undef FRAG
#undef FENCE
#undef BAR
#undef VMW3
#undef VMW0
}

// ---------------- final reduce ----------------
__global__ __launch_bounds__(256)
void finalize_kernel(const float4* __restrict__ partials, float* __restrict__ out) {
    int t = threadIdx.x;
    double p = 0, n = 0, c = 0, k = 0;
    for (int s = t; s < NBLK; s += 256) {
        float4 v = partials[s];
        p += v.x; n += v.y; c += v.z; k += v.w;
    }
    __shared__ double sh[256][4];
    sh[t][0] = p; sh[t][1] = n; sh[t][2] = c; sh[t][3] = k;
    __syncthreads();
    for (int o = 128; o; o >>= 1) {
        if (t < o) {
            sh[t][0] += sh[t+o][0]; sh[t][1] += sh[t+o][1];
            sh[t][2] += sh[t+o][2]; sh[t][3] += sh[t+o][3];
        }
        __syncthreads();
    }
    if (t == 0) {
        double npos = sh[0][3] < 1.0 ? 1.0 : sh[0][3];
        double total = (double)NROWS * (NROWS - 1) * 0.5;
        double nneg = total - sh[0][3]; if (nneg < 1.0) nneg = 1.0;
        double loss = sh[0][0] / npos + sh[0][1] / nneg
                    + sh[0][2] / ((double)NROWS * (double)NROWS);
        out[0] = (float)loss;
    }
}

extern "C" void kernel_launch(void* const* d_in, const int* in_sizes, int n_in,
                              void* d_out, int out_size, void* d_ws, size_t ws_size,
                              hipStream_t stream) {
    const float* X      = (const float*)d_in[0];
    const float* Y      = (const float*)d_in[1];
    const int*   labels = (const int*)d_in[2];
    float* out = (float*)d_out;
    char*  ws  = (char*)d_ws;

    // ws: partials (128KB) | SXa (32KB) | TB (64KB) | Zf4 (16384*384 = 6.3MB)
    float4* partials = (float4*)ws;
    float*  SXa      = (float*)(ws + 128*1024);
    float*  TB       = (float*)(ws + 128*1024 + 32*1024);
    uchar*  Zf4      = (uchar*)(ws + 256*1024);

    prep<<<NROWS, 256, 0, stream>>>(X, Y, SXa, TB, Zf4);
    gemm_loss<<<NBLK, 512, 0, stream>>>(Zf4, labels, SXa, TB, partials);
    finalize_kernel<<<1, 256, 0, stream>>>(partials, out);
}

// Round 15
// 93.529 us; speedup vs baseline: 1.0382x; 1.0382x over previous
//
#include <hip/hip_runtime.h>
#include <hip/hip_bf16.h>
#include <stdint.h>
#include <math.h>

#define NROWS  8192
#define DIM    768                        // elements per row
#define DIMB   384                        // bytes per row in fp4 (4 bits/elem)
#define BKB    64                         // K-tile bytes (128 elements)
#define NKT    6                          // 768 / 128
#define BM     256
#define BN     128
#define EPSV   1e-6f
#define NTI    32                         // 8192/BM
#define NTJ    64                         // 8192/BN
#define NJN    (NTI * NTJ)                // 2048 X-vs-Y tiles
#define NJJ    1056                       // JJ tiles: sum_{ti}(64-2ti)
#define NBLK   (NJN + NJJ)                // 3104 = 8 * 388 (XCD-divisible)

typedef __attribute__((ext_vector_type(4))) int   int4v;
typedef __attribute__((ext_vector_type(8))) int   int8v;
typedef __attribute__((ext_vector_type(4))) float f32x4;
typedef unsigned char uchar;

// async global->LDS, 16B per lane; LDS dest is wave-uniform base (+lane*16 by HW)
__device__ __forceinline__ void gload16(const void* g, void* l) {
    __builtin_amdgcn_global_load_lds(
        (const __attribute__((address_space(1))) void*)g,
        (__attribute__((address_space(3))) void*)l,
        16, 0, 0);
}

// fp32 -> fp4 e2m1 nibble, round-to-nearest. Levels {0,.5,1,1.5,2,3,4,6}.
__device__ __forceinline__ uint32_t f2fp4(float x) {
    float a = fabsf(x);
    uint32_t c;
    if (a < 1.25f)      c = a < 0.25f ? 0u : (a < 0.75f ? 1u : 2u);
    else if (a < 2.5f)  c = a < 1.75f ? 3u : 4u;
    else                c = a < 3.5f ? 5u : (a < 5.0f ? 6u : 7u);
    return c | (x < 0.f ? 8u : 0u);
}

// ------- prep: fp4-e2m1 convert into Z=[X;Y], folded row stats (exact fp32) -------
// 2 rows per block: threads [0,128) = row 2*bid, [128,256) = row 2*bid+1.
__global__ __launch_bounds__(256)
void prep(const float* __restrict__ X, const float* __restrict__ Y,
          float* __restrict__ SXa, float* __restrict__ TB,
          uchar* __restrict__ Zf4) {
    const int row = 2 * blockIdx.x + (threadIdx.x >> 7);   // 0..16383
    const int tt  = threadIdx.x & 127;
    const bool isX = row < NROWS;
    const float* p = (isX ? X : Y) + (size_t)(isX ? row : row - NROWS) * DIM;
    uint32_t* q = (uint32_t*)(Zf4 + (size_t)row * DIMB);
    float s = 0.f, qs = 0.f;
    if (tt < 96) {                         // 96 * 8 = 768 elems
        float4 v0 = *(const float4*)(p + 8 * tt);
        float4 v1 = *(const float4*)(p + 8 * tt + 4);
        uint32_t u = f2fp4(v0.x)        | (f2fp4(v0.y) << 4)  |
                     (f2fp4(v0.z) << 8) | (f2fp4(v0.w) << 12) |
                     (f2fp4(v1.x) << 16)| (f2fp4(v1.y) << 20) |
                     (f2fp4(v1.z) << 24)| (f2fp4(v1.w) << 28);
        q[tt] = u;
        s  = v0.x+v0.y+v0.z+v0.w + v1.x+v1.y+v1.z+v1.w;
        qs = v0.x*v0.x+v0.y*v0.y+v0.z*v0.z+v0.w*v0.w
           + v1.x*v1.x+v1.y*v1.y+v1.z*v1.z+v1.w*v1.w;
    }
    #pragma unroll
    for (int o = 32; o; o >>= 1) { s += __shfl_down(s, o); qs += __shfl_down(qs, o); }
    __shared__ float sh[8];
    const int wave = threadIdx.x >> 6, lane = threadIdx.x & 63;
    if (lane == 0) { sh[wave] = s; sh[4 + wave] = qs; }
    __syncthreads();
    if (tt == 0) {                          // thread 0 (row even) and 128 (row odd)
        const int w0 = (threadIdx.x >> 7) * 2;
        float ss = sh[w0] + sh[w0 + 1];
        float qq = sh[4 + w0] + sh[4 + w0 + 1];
        if (isX) SXa[row] = qq + 2.f*EPSV*ss;
        TB[row] = qq - 2.f*EPSV*ss + (float)DIM*EPSV*EPSV;
    }
}

// ------- fused MX-fp4 GEMM, 256x128 tile, 8 waves (4Mx2N), 3-deep pipeline -------
// (r13 structure; r15 delta: slot-permutation LDS swizzle v2.)
// Layout: 16B block (row, c) of a tile lives at LDS byte
//   (row>>4)*1024 + (row&15)*64 + (((c + row + ((row>>2)&3)) & 3) << 4)
// -> bank groups 2-way per 16-lane fragment read (free, m136); v1's XOR-only
// swizzle left a 4-way clump (lanes rr=0 mod 4), 4.77M conflict cy/dispatch.
// Write side: gload16 chunk slot l holds (rl=l>>2, c=((l&3)-(l>>2)-(l>>4))&3);
// the inverse permutation goes into the per-lane GLOBAL source col (coalescing
// unchanged: permutes within each row's 64B slice). Read offset is per-thread
// constant: (rr>>2)&3 == lrow>>2 and rr&3 == lrow&3 (row bases = 16-aligned).
// Register budget: acc 64 AGPR + ~60 VGPR <= 128 cap at 2 blocks/CU
// (launch_bounds(512,4)). Do NOT add live state across barriers.
__global__ __launch_bounds__(512, 4)
void gemm_loss(const uchar* __restrict__ Z, const int* __restrict__ labels,
               const float* __restrict__ SXa, const float* __restrict__ TB,
               float4* __restrict__ partials) {
    // bijective XCD swizzle: 3104 = 8 * 388
    const int bid = (blockIdx.x & 7) * (NBLK / 8) + (blockIdx.x >> 3);
    const int t = threadIdx.x;

    int ti, tj, jrow0;                      // jrow0 = B-side row base in Z
    bool jj;
    if (bid < NJN) {
        jj = false; ti = bid >> 6; tj = bid & 63; jrow0 = NROWS + tj * BN;
    } else {
        jj = true;
        int u = bid - NJN;                  // 0..1055; row ti has 64-2ti entries
        int t0 = (int)((65.0 - sqrt(65.0*65.0 - 4.0*(double)u)) * 0.5);
        if (t0 < 0) t0 = 0; if (t0 > 31) t0 = 31;
        while (t0 < 31 && (t0 + 1) * (65 - (t0 + 1)) <= u) ++t0;
        while (t0 > 0  && t0 * (65 - t0) > u) --t0;
        ti = t0; tj = 2*ti + (u - ti * (65 - ti)); jrow0 = tj * BN;
    }
    const int i0 = ti * BM;
    const int tjc = tj * BN;                // B-side column base (labels/lt)

    __shared__ __align__(16) uchar Asm[3][BM * BKB];   // 16 KB per buf
    __shared__ __align__(16) uchar Bsm[3][BN * BKB];   // 8 KB per buf
    __shared__ float red[8][4];

    const int wave = t >> 6, lane = t & 63;
    const int wrow = wave >> 1;             // 0..3 (M quarter: 64 rows)
    const int wcol = wave & 1;              // 0..1 (N half: 64 cols)

    // staging: chunk = 16 rows x 64B = 1KB; lane l -> row +(l>>2);
    // slot-perm inverse: global 16B-col c = ((l&3) - (l>>2) - (l>>4)) & 3
    const int cS = ((((lane & 3) - (lane >> 2) - (lane >> 4)) & 3) << 4);
    const uchar* pAs = Z + (size_t)(i0 + 16*wave + (lane >> 2))    * DIMB + cS;
    const uchar* pBs = Z + (size_t)(jrow0 + 16*wave + (lane >> 2)) * DIMB + cS;

    const int lrow = lane & 15;
    // per-thread-constant swizzled col offset for fragment reads (deriv above)
    const int swc = ((((lane >> 4) + lrow + (lrow >> 2)) & 3) << 4);

    f32x4 acc[4][4] = {};

#define STAGE(b, kb)                                                           \
    do {                                                                       \
        gload16(pAs + (kb), &Asm[b][wave * 1024]);                             \
        gload16(pAs + (size_t)128 * DIMB + (kb), &Asm[b][(wave + 8) * 1024]);  \
        gload16(pBs + (kb), &Bsm[b][wave * 1024]);                             \
    } while (0)

#define COMPUTE(b)                                                             \
    do {                                                                       \
        int8v bfr[4];                                                          \
        _Pragma("unroll")                                                      \
        for (int ni = 0; ni < 4; ++ni) {                                       \
            int rr = wcol*64 + ni*16 + lrow;                                   \
            int4v lo = *(const int4v*)&Bsm[b][rr*64 + swc];                    \
            bfr[ni] = __builtin_shufflevector(lo, (int4v){0,0,0,0},            \
                                              0,1,2,3,4,5,6,7);                \
        }                                                                      \
        __builtin_amdgcn_s_setprio(1);                                         \
        _Pragma("unroll")                                                      \
        for (int mi = 0; mi < 4; ++mi) {                                       \
            int rr = wrow*64 + mi*16 + lrow;                                   \
            int4v lo = *(const int4v*)&Asm[b][rr*64 + swc];                    \
            int8v afr = __builtin_shufflevector(lo, (int4v){0,0,0,0},          \
                                                0,1,2,3,4,5,6,7);              \
            _Pragma("unroll")                                                  \
            for (int ni = 0; ni < 4; ++ni)                                     \
                acc[mi][ni] = __builtin_amdgcn_mfma_scale_f32_16x16x128_f8f6f4( \
                    afr, bfr[ni], acc[mi][ni], 4, 4,                           \
                    0, 0x7F7F7F7Fu, 0, 0x7F7F7F7Fu);                           \
        }                                                                      \
        __builtin_amdgcn_s_setprio(0);                                         \
    } while (0)

#define FENCE() asm volatile("" ::: "memory")
#define BAR()   do { FENCE(); __builtin_amdgcn_s_barrier(); FENCE(); } while (0)
#define VMW3()  asm volatile("s_waitcnt vmcnt(3)" ::: "memory")
#define VMW0()  asm volatile("s_waitcnt vmcnt(0)" ::: "memory")

    // prologue: stage tiles 0,1; retire tile 0 (VMW3 leaves tile 1's 3 in flight)
    STAGE(0, 0);
    STAGE(1, BKB);
    VMW3();
    BAR();

    #pragma unroll
    for (int kt = 0; kt < NKT; ++kt) {
        if (kt < NKT - 2) STAGE((kt + 2) % 3, (kt + 2) * BKB);
        COMPUTE(kt % 3);
        if (kt < NKT - 2)      { VMW3(); BAR(); }   // retire tile kt+1
        else if (kt == NKT - 2){ VMW0(); BAR(); }   // tail: tile kt+1 fully in
    }

    // -------- epilogue (C/D: col=lane&15, row=(lane>>4)*4+reg) --------
    const int il = wrow*64 + ((lane >> 4) << 2);  // + mi*16 + r
    const int jl = wcol*64 + (lane & 15);         // + ni*16

    float tbv[4];
    #pragma unroll
    for (int ni = 0; ni < 4; ++ni)
        tbv[ni] = TB[jrow0 + jl + ni*16];

    float pos = 0.f, neg = 0.f, cross = 0.f, cnt = 0.f;
    float mn = 1e30f;                        // min over valid neg/cross cands

    if (jj) {
        int labj[4];
        #pragma unroll
        for (int ni = 0; ni < 4; ++ni)
            labj[ni] = labels[tjc + jl + ni*16];
        const bool fullup = (tj >= 2*ti + 2);    // tile strictly above diagonal
        #pragma unroll
        for (int mi = 0; mi < 4; ++mi) {
            float4 sx4 = *(const float4*)&SXa[i0 + il + mi*16];
            int4   la4 = *(const int4*)&labels[i0 + il + mi*16];
            float sxr[4] = {sx4.x, sx4.y, sx4.z, sx4.w};
            int   lar[4] = {la4.x, la4.y, la4.z, la4.w};
            #pragma unroll
            for (int ni = 0; ni < 4; ++ni)
                #pragma unroll
                for (int r = 0; r < 4; ++r) {
                    float d2 = __builtin_fmaf(-2.f, acc[mi][ni][r],
                                              sxr[r] + tbv[ni]);
                    bool lt   = fullup | ((i0 + il + mi*16 + r) < (tjc + jl + ni*16));
                    bool same = (lar[r] == labj[ni]);
                    if (lt & same) { pos += fmaxf(d2, 0.f); cnt += 1.f; }
                    mn = fminf(mn, (lt & !same) ? d2 : 1e30f);
                }
        }
    } else {
        #pragma unroll
        for (int mi = 0; mi < 4; ++mi) {
            float4 sx4 = *(const float4*)&SXa[i0 + il + mi*16];
            float sxr[4] = {sx4.x, sx4.y, sx4.z, sx4.w};
            #pragma unroll
            for (int ni = 0; ni < 4; ++ni)
                #pragma unroll
                for (int r = 0; r < 4; ++r) {
                    float d2 = __builtin_fmaf(-2.f, acc[mi][ni][r],
                                              sxr[r] + tbv[ni]);
                    mn = fminf(mn, d2);
                }
        }
    }

    // rare exact path: only if some margin-active pair exists (never on this data)
    if (__any(mn < 1.f)) {
        int labj[4] = {0,0,0,0};
        if (jj)
            #pragma unroll
            for (int ni = 0; ni < 4; ++ni)
                labj[ni] = labels[tjc + jl + ni*16];
        const bool fullup = jj && (tj >= 2*ti + 2);
        #pragma unroll
        for (int mi = 0; mi < 4; ++mi) {
            float4 sx4 = *(const float4*)&SXa[i0 + il + mi*16];
            float sxr[4] = {sx4.x, sx4.y, sx4.z, sx4.w};
            int lar[4] = {0,0,0,0};
            if (jj) {
                int4 la4 = *(const int4*)&labels[i0 + il + mi*16];
                lar[0]=la4.x; lar[1]=la4.y; lar[2]=la4.z; lar[3]=la4.w;
            }
            #pragma unroll
            for (int ni = 0; ni < 4; ++ni)
                #pragma unroll
                for (int r = 0; r < 4; ++r) {
                    float d2 = __builtin_fmaf(-2.f, acc[mi][ni][r],
                                              sxr[r] + tbv[ni]);
                    d2 = fmaxf(d2, 0.f);
                    float dist = sqrtf(fmaxf(d2, 1e-12f));
                    float m = fmaxf(1.f - dist, 0.f);
                    float s2 = m * m;
                    if (jj) {
                        bool lt   = fullup | ((i0 + il + mi*16 + r) < (tjc + jl + ni*16));
                        bool same = (lar[r] == labj[ni]);
                        if (lt & !same) neg += s2;
                    } else {
                        cross += s2;
                    }
                }
        }
    }

    #pragma unroll
    for (int o = 32; o; o >>= 1) {
        pos   += __shfl_down(pos, o);
        neg   += __shfl_down(neg, o);
        cross += __shfl_down(cross, o);
        cnt   += __shfl_down(cnt, o);
    }
    if (lane == 0) { red[wave][0] = pos; red[wave][1] = neg;
                     red[wave][2] = cross; red[wave][3] = cnt; }
    __syncthreads();
    if (t == 0) {
        float4 v = {0.f, 0.f, 0.f, 0.f};
        #pragma unroll
        for (int w = 0; w < 8; ++w) {
            v.x += red[w][0]; v.y += red[w][1];
            v.z += red[w][2]; v.w += red[w][3];
        }
        partials[bid] = v;
    }
#undef STAGE
#undef COMPUTE
#undef FENCE
#undef BAR
#undef VMW3
#undef VMW0
}

// ---------------- final reduce ----------------
__global__ __launch_bounds__(256)
void finalize_kernel(const float4* __restrict__ partials, float* __restrict__ out) {
    int t = threadIdx.x;
    double p = 0, n = 0, c = 0, k = 0;
    for (int s = t; s < NBLK; s += 256) {
        float4 v = partials[s];
        p += v.x; n += v.y; c += v.z; k += v.w;
    }
    __shared__ double sh[256][4];
    sh[t][0] = p; sh[t][1] = n; sh[t][2] = c; sh[t][3] = k;
    __syncthreads();
    for (int o = 128; o; o >>= 1) {
        if (t < o) {
            sh[t][0] += sh[t+o][0]; sh[t][1] += sh[t+o][1];
            sh[t][2] += sh[t+o][2]; sh[t][3] += sh[t+o][3];
        }
        __syncthreads();
    }
    if (t == 0) {
        double npos = sh[0][3] < 1.0 ? 1.0 : sh[0][3];
        double total = (double)NROWS * (NROWS - 1) * 0.5;
        double nneg = total - sh[0][3]; if (nneg < 1.0) nneg = 1.0;
        double loss = sh[0][0] / npos + sh[0][1] / nneg
                    + sh[0][2] / ((double)NROWS * (double)NROWS);
        out[0] = (float)loss;
    }
}

extern "C" void kernel_launch(void* const* d_in, const int* in_sizes, int n_in,
                              void* d_out, int out_size, void* d_ws, size_t ws_size,
                              hipStream_t stream) {
    const float* X      = (const float*)d_in[0];
    const float* Y      = (const float*)d_in[1];
    const int*   labels = (const int*)d_in[2];
    float* out = (float*)d_out;
    char*  ws  = (char*)d_ws;

    // ws: partials (128KB) | SXa (32KB) | TB (64KB) | Zf4 (16384*384 = 6.3MB)
    float4* partials = (float4*)ws;
    float*  SXa      = (float*)(ws + 128*1024);
    float*  TB       = (float*)(ws + 128*1024 + 32*1024);
    uchar*  Zf4      = (uchar*)(ws + 256*1024);

    prep<<<NROWS, 256, 0, stream>>>(X, Y, SXa, TB, Zf4);
    gemm_loss<<<NBLK, 512, 0, stream>>>(Zf4, labels, SXa, TB, partials);
    finalize_kernel<<<1, 256, 0, stream>>>(partials, out);
}